// Round 1
// baseline (292.254 us; speedup 1.0000x reference)
//
#include <hip/hip_runtime.h>
#include <math.h>

#define STEPS 3
#define BS 8
#define NCH 256
#define H 64
#define W 64
#define NO 3
#define ROWS 4
#define TILE_H (ROWS + 2)
#define TILE_W (W + 2)
#define TILE_N (TILE_H * TILE_W)   // 396
#define UP 8
#define OH (H * UP)
#define OW (W * UP)

// Kernel 1: per (step, b, row-tile) block computes dmap[step,b, y0..y0+3, 0..63]
// fully fused: depthwise 3x3 corr (3 objects) -> softmax over objects ->
// weighted sum -> dot with w_head -> +bias -> relu.
__global__ __launch_bounds__(256) void loca_dmap_kernel(
    const float* __restrict__ f_e,     // [BS, NCH, H, W]
    const float* __restrict__ ap,      // [STEPS, NO*9, BS, NCH]
    const float* __restrict__ w_head,  // [NCH]
    const float* __restrict__ b_head,  // [1]
    float* __restrict__ dmap)          // [STEPS*BS, H, W]
{
    __shared__ float tile[2][TILE_N];
    __shared__ float wsm[2][32];       // 27 used

    const int tid = threadIdx.x;
    const int t   = blockIdx.x;        // row tile 0..15
    const int b   = blockIdx.y;
    const int i   = blockIdx.z;
    const int ly  = tid >> 6;          // 0..3 (row within tile)
    const int lx  = tid & 63;          // col
    const int y0  = t * ROWS;

    // Precompute the (at most 2) staging slots this thread owns; they are
    // channel-invariant (only the base pointer changes per channel).
    int  ld_dst[2];
    int  ld_src[2];
    bool ld_val[2];   // slot exists (idx < TILE_N)
    bool ld_inb[2];   // source in-bounds (else zero-pad)
    #pragma unroll
    for (int s = 0; s < 2; ++s) {
        int idx = tid + s * 256;
        ld_val[s] = (idx < TILE_N);
        int r  = idx / TILE_W;
        int cc = idx - r * TILE_W;
        int gy = y0 - 1 + r;
        int gx = cc - 1;
        ld_dst[s] = idx;
        ld_inb[s] = (gy >= 0 && gy < H && gx >= 0 && gx < W);
        ld_src[s] = gy * W + gx;
    }

    const float* fb = f_e + (size_t)b * NCH * H * W;
    const float* apb = ap + ((size_t)i * NO * 9 * BS + b) * (size_t)NCH;
    // ap index for (i, j, b, c): ((i*27 + j)*BS + b)*NCH + c = apb + j*BS*NCH + c

    // Preload channel 0 into buffer 0
    {
        const float* fc = fb;  // channel 0
        #pragma unroll
        for (int s = 0; s < 2; ++s)
            if (ld_val[s])
                tile[0][ld_dst[s]] = ld_inb[s] ? fc[ld_src[s]] : 0.0f;
        if (tid < NO * 9)
            wsm[0][tid] = apb[(size_t)tid * BS * NCH];
    }

    float acc = 0.0f;

    for (int c = 0; c < NCH; ++c) {
        const int p = c & 1;
        __syncthreads();
        // Prefetch channel c+1 into buffer 1-p (written only after barrier,
        // read only after next barrier -> race-free with one barrier/channel)
        if (c + 1 < NCH) {
            const float* fc = fb + (size_t)(c + 1) * H * W;
            #pragma unroll
            for (int s = 0; s < 2; ++s)
                if (ld_val[s])
                    tile[1 - p][ld_dst[s]] = ld_inb[s] ? fc[ld_src[s]] : 0.0f;
            if (tid < NO * 9)
                wsm[1 - p][tid] = apb[(size_t)tid * BS * NCH + (c + 1)];
        }

        // Compute from buffer p
        const float* tl = tile[p];
        const float* wv = wsm[p];
        float r0 = 0.0f, r1 = 0.0f, r2 = 0.0f;
        #pragma unroll
        for (int dy = 0; dy < 3; ++dy) {
            #pragma unroll
            for (int dx = 0; dx < 3; ++dx) {
                float v = tl[(ly + dy) * TILE_W + (lx + dx)];
                int j = dy * 3 + dx;
                r0 = fmaf(v, wv[j],      r0);
                r1 = fmaf(v, wv[9 + j],  r1);
                r2 = fmaf(v, wv[18 + j], r2);
            }
        }
        // softmax over 3 objects, weighted sum
        float m  = fmaxf(r0, fmaxf(r1, r2));
        float e0 = __expf(r0 - m);
        float e1 = __expf(r1 - m);
        float e2 = __expf(r2 - m);
        float num = fmaf(e0, r0, fmaf(e1, r1, e2 * r2));
        float den = e0 + e1 + e2;
#if __has_builtin(__builtin_amdgcn_rcpf)
        float red = num * __builtin_amdgcn_rcpf(den);
#else
        float red = num / den;
#endif
        acc = fmaf(w_head[c], red, acc);
    }

    float dv = fmaxf(acc + b_head[0], 0.0f);
    dmap[(((size_t)i * BS + b) * H + (y0 + ly)) * W + lx] = dv;
}

// Kernel 2: bilinear 8x upsample (half-pixel centers, edge clamp) of dmap
// [STEPS*BS, 64, 64] -> out [STEPS*BS, 512, 512], float4 stores.
__global__ __launch_bounds__(256) void loca_upsample_kernel(
    const float* __restrict__ dmap, float* __restrict__ out)
{
    const int idx = blockIdx.x * 256 + threadIdx.x;  // one float4 group
    const int gx   = idx & (OW / 4 - 1);             // 0..127
    const int rest = idx >> 7;
    const int Y    = rest & (OH - 1);                // 0..511
    const int ib   = rest >> 9;                      // 0..23

    const float* d = dmap + (size_t)ib * H * W;

    float yin = (Y + 0.5f) * 0.125f - 0.5f;
    float fy0 = floorf(yin);
    int   iy  = (int)fy0;
    float fy  = yin - fy0;
    int y0c = min(max(iy, 0), H - 1);
    int y1c = min(max(iy + 1, 0), H - 1);
    const float* row0 = d + y0c * W;
    const float* row1 = d + y1c * W;

    float4 o;
    float* op = &o.x;
    #pragma unroll
    for (int j = 0; j < 4; ++j) {
        int X = gx * 4 + j;
        float xin = (X + 0.5f) * 0.125f - 0.5f;
        float fx0 = floorf(xin);
        int   ix  = (int)fx0;
        float fx  = xin - fx0;
        int x0c = min(max(ix, 0), W - 1);
        int x1c = min(max(ix + 1, 0), W - 1);
        float a00 = row0[x0c], a01 = row0[x1c];
        float a10 = row1[x0c], a11 = row1[x1c];
        float v0 = a00 + fx * (a01 - a00);
        float v1 = a10 + fx * (a11 - a10);
        op[j] = v0 + fy * (v1 - v0);
    }
    ((float4*)out)[idx] = o;
}

extern "C" void kernel_launch(void* const* d_in, const int* in_sizes, int n_in,
                              void* d_out, int out_size, void* d_ws, size_t ws_size,
                              hipStream_t stream) {
    const float* f_e    = (const float*)d_in[0];
    const float* ap     = (const float*)d_in[1];
    const float* w_head = (const float*)d_in[2];
    const float* b_head = (const float*)d_in[3];
    float* out  = (float*)d_out;
    float* dmap = (float*)d_ws;   // STEPS*BS*H*W floats = 393216 B

    dim3 g1(H / ROWS, BS, STEPS);  // 16 x 8 x 3 = 384 blocks
    loca_dmap_kernel<<<g1, 256, 0, stream>>>(f_e, ap, w_head, b_head, dmap);

    const int groups = STEPS * BS * OH * OW / 4;  // 1,572,864
    loca_upsample_kernel<<<groups / 256, 256, 0, stream>>>(dmap, out);
}

// Round 2
// 142.788 us; speedup vs baseline: 2.0468x; 2.0468x over previous
//
#include <hip/hip_runtime.h>
#include <math.h>

#define STEPS 3
#define BS 8
#define NCH 256
#define H 64
#define W 64
#define UP 8
#define OH (H*UP)
#define OW (W*UP)
#define G 32              // channel groups (atomic partial sums)
#define CPG (NCH/G)       // 8 channels per group
#define WREC 32           // floats per packed weight record (27 taps + w_head + pad)
#define DMAP_FLOATS (STEPS*BS*H*W)   // 98304

// ---- prep: transpose prototypes into contiguous per-channel records -------
// wt[((i*BS+b)*NCH + c)*WREC + j] = j<27 ? ap[((i*27+j)*BS+b)*NCH+c] : w_head[c]
__global__ __launch_bounds__(256) void loca_prep(
    const float* __restrict__ ap, const float* __restrict__ w_head,
    float* __restrict__ wt)
{
    int t = blockIdx.x * 256 + threadIdx.x;
    if (t >= STEPS * 28 * BS * NCH) return;
    int c = t & (NCH - 1);
    int r = t >> 8;
    int b = r & (BS - 1);
    r >>= 3;
    int j = r % 28;
    int i = r / 28;
    float v = (j < 27) ? ap[(((size_t)i * 27 + j) * BS + b) * NCH + c] : w_head[c];
    wt[(((size_t)i * BS + b) * NCH + c) * WREC + j] = v;
}

// ---- fused dmap: depthwise 3x3 corr -> obj softmax -> weighted sum -> head dot
// Barrier-free, LDS-free. Each lane: one row (lane>>4), 4 cols (lane&15)*4.
// Channel groups accumulate via atomicAdd into dmap (pre-bias, pre-relu sums).
__global__ __launch_bounds__(256) void loca_dmap(
    const float* __restrict__ f_e,   // [BS, NCH, H, W]
    const float* __restrict__ wt,    // [STEPS*BS*NCH, WREC]
    float* __restrict__ dmap)        // [STEPS*BS, H, W] (accumulator)
{
    const int lane = threadIdx.x & 63;
    const int wid  = threadIdx.x >> 6;          // wave 0..3
    const int i    = blockIdx.z >> 5;           // step
    const int g    = blockIdx.z & (G - 1);      // channel group
    const int b    = blockIdx.y;
    const int row  = blockIdx.x * 16 + wid * 4 + (lane >> 4);  // 0..63
    const int xg   = lane & 15;                 // float4 group within row
    const int c0   = g * CPG;

    const float m_m1 = (row > 0)     ? 1.f : 0.f;
    const float m_p1 = (row < H - 1) ? 1.f : 0.f;
    const int r_m1 = row > 0     ? row - 1 : 0;
    const int r_p1 = row < H - 1 ? row + 1 : H - 1;

    const float* fb = f_e + ((size_t)b * NCH + c0) * (H * W);
    const float* wb = wt  + ((size_t)(i * BS + b) * NCH + c0) * WREC;

    float acc[4] = {0.f, 0.f, 0.f, 0.f};

    #pragma unroll 2
    for (int cc = 0; cc < CPG; ++cc) {
        const float* fc = fb + cc * (H * W);
        float4 vm = ((const float4*)(fc + r_m1 * W))[xg];
        float4 v0 = ((const float4*)(fc + row  * W))[xg];
        float4 vp = ((const float4*)(fc + r_p1 * W))[xg];
        vm.x *= m_m1; vm.y *= m_m1; vm.z *= m_m1; vm.w *= m_m1;
        vp.x *= m_p1; vp.y *= m_p1; vp.z *= m_p1; vp.w *= m_p1;

        // horizontal neighbors across lanes; 16-lane segment edges == image edges
        float Lm = __shfl_up(vm.w, 1);
        float L0 = __shfl_up(v0.w, 1);
        float Lp = __shfl_up(vp.w, 1);
        float Rm = __shfl_down(vm.x, 1);
        float R0 = __shfl_down(v0.x, 1);
        float Rp = __shfl_down(vp.x, 1);
        if (xg == 0)  { Lm = 0.f; L0 = 0.f; Lp = 0.f; }
        if (xg == 15) { Rm = 0.f; R0 = 0.f; Rp = 0.f; }

        float am[6]  = {Lm, vm.x, vm.y, vm.z, vm.w, Rm};
        float a0[6]  = {L0, v0.x, v0.y, v0.z, v0.w, R0};
        float apv[6] = {Lp, vp.x, vp.y, vp.z, vp.w, Rp};

        const float* w = wb + cc * WREC;   // wave-uniform -> s_load
        float wh = w[27];

        #pragma unroll
        for (int k = 0; k < 4; ++k) {
            float r_[3];
            #pragma unroll
            for (int o = 0; o < 3; ++o) {
                const float* q = w + o * 9;
                float t = am[k] * q[0];
                t = fmaf(am[k+1],  q[1], t);
                t = fmaf(am[k+2],  q[2], t);
                t = fmaf(a0[k],    q[3], t);
                t = fmaf(a0[k+1],  q[4], t);
                t = fmaf(a0[k+2],  q[5], t);
                t = fmaf(apv[k],   q[6], t);
                t = fmaf(apv[k+1], q[7], t);
                t = fmaf(apv[k+2], q[8], t);
                r_[o] = t;
            }
            float mx = fmaxf(r_[0], fmaxf(r_[1], r_[2]));
            float e0 = __expf(r_[0] - mx);
            float e1 = __expf(r_[1] - mx);
            float e2 = __expf(r_[2] - mx);
            float num = fmaf(e0, r_[0], fmaf(e1, r_[1], e2 * r_[2]));
            float den = e0 + e1 + e2;
#if __has_builtin(__builtin_amdgcn_rcpf)
            float red = num * __builtin_amdgcn_rcpf(den);
#else
            float red = num / den;
#endif
            acc[k] = fmaf(wh, red, acc[k]);
        }
    }

    float* dp = dmap + (size_t)(i * BS + b) * (H * W) + row * W + xg * 4;
    #pragma unroll
    for (int k = 0; k < 4; ++k) {
#if defined(__gfx90a__) || defined(__gfx940__) || defined(__gfx941__) || defined(__gfx942__) || defined(__gfx950__)
        unsafeAtomicAdd(dp + k, acc[k]);
#else
        atomicAdd(dp + k, acc[k]);
#endif
    }
}

// ---- bilinear 8x upsample with fused bias+relu ----------------------------
__global__ __launch_bounds__(256) void loca_upsample(
    const float* __restrict__ dmap, const float* __restrict__ b_head,
    float* __restrict__ out)
{
    const int idx  = blockIdx.x * 256 + threadIdx.x;   // one float4 group
    const int gx   = idx & (OW / 4 - 1);               // 0..127
    const int rest = idx >> 7;
    const int Y    = rest & (OH - 1);                  // 0..511
    const int ib   = rest >> 9;                        // 0..23
    const float bias = b_head[0];

    const float* d = dmap + (size_t)ib * H * W;

    float yin = (Y + 0.5f) * 0.125f - 0.5f;
    float fy0 = floorf(yin);
    int   iy  = (int)fy0;
    float fy  = yin - fy0;
    int y0c = min(max(iy, 0), H - 1);
    int y1c = min(max(iy + 1, 0), H - 1);
    const float* row0 = d + y0c * W;
    const float* row1 = d + y1c * W;

    float4 o;
    float* op = &o.x;
    #pragma unroll
    for (int j = 0; j < 4; ++j) {
        int X = gx * 4 + j;
        float xin = (X + 0.5f) * 0.125f - 0.5f;
        float fx0 = floorf(xin);
        int   ix  = (int)fx0;
        float fx  = xin - fx0;
        int x0c = min(max(ix, 0), W - 1);
        int x1c = min(max(ix + 1, 0), W - 1);
        float a00 = fmaxf(row0[x0c] + bias, 0.f);
        float a01 = fmaxf(row0[x1c] + bias, 0.f);
        float a10 = fmaxf(row1[x0c] + bias, 0.f);
        float a11 = fmaxf(row1[x1c] + bias, 0.f);
        float v0 = a00 + fx * (a01 - a00);
        float v1 = a10 + fx * (a11 - a10);
        op[j] = v0 + fy * (v1 - v0);
    }
    ((float4*)out)[idx] = o;
}

extern "C" void kernel_launch(void* const* d_in, const int* in_sizes, int n_in,
                              void* d_out, int out_size, void* d_ws, size_t ws_size,
                              hipStream_t stream) {
    const float* f_e    = (const float*)d_in[0];
    const float* ap     = (const float*)d_in[1];
    const float* w_head = (const float*)d_in[2];
    const float* b_head = (const float*)d_in[3];
    float* out  = (float*)d_out;
    float* dmap = (float*)d_ws;                      // 98304 floats
    float* wt   = dmap + DMAP_FLOATS;                // 196608 floats

    hipMemsetAsync(dmap, 0, DMAP_FLOATS * sizeof(float), stream);

    loca_prep<<<(STEPS * 28 * BS * NCH + 255) / 256, 256, 0, stream>>>(ap, w_head, wt);

    dim3 g1(H / 16, BS, STEPS * G);   // 4 x 8 x 96 = 3072 blocks
    loca_dmap<<<g1, 256, 0, stream>>>(f_e, wt, dmap);

    const int groups = STEPS * BS * OH * OW / 4;     // 1,572,864
    loca_upsample<<<groups / 256, 256, 0, stream>>>(dmap, b_head, out);
}